// Round 1
// baseline (575.570 us; speedup 1.0000x reference)
//
#include <hip/hip_runtime.h>

// GCN encoder: out = A @ ( relu(A @ (X W1)) W2 ),  A = COO scatter (dst <- src)
// N=100000 nodes, E=1600000 edges, F_IN=128, H1=64, H2=32, all f32.

constexpr int N_NODES = 100000;
constexpr int N_EDGES = 1600000;
constexpr int F_IN = 128;
constexpr int H1 = 64;
constexpr int H2 = 32;

// ---------------- GEMM1: X[N,128] @ W1[128,64] -> out[N,64] ----------------
// One output row per thread; W1 staged in LDS (reads are wave-uniform -> broadcast).
__global__ __launch_bounds__(256) void gemm_xw1(
    const float* __restrict__ X, const float* __restrict__ W1,
    float* __restrict__ out)
{
    __shared__ float ws[F_IN * H1];                    // 32 KiB
    for (int i = threadIdx.x; i < F_IN * H1; i += 256) ws[i] = W1[i];
    __syncthreads();

    int row = blockIdx.x * 256 + threadIdx.x;
    if (row >= N_NODES) return;

    const float4* xr = reinterpret_cast<const float4*>(X + (size_t)row * F_IN);
    float4 acc[H1 / 4];
#pragma unroll
    for (int j = 0; j < H1 / 4; ++j) acc[j] = make_float4(0.f, 0.f, 0.f, 0.f);

    for (int k4 = 0; k4 < F_IN / 4; ++k4) {
        float4 xv = xr[k4];
#pragma unroll
        for (int kk = 0; kk < 4; ++kk) {
            float xk = (kk == 0) ? xv.x : (kk == 1) ? xv.y : (kk == 2) ? xv.z : xv.w;
            const float4* wr = reinterpret_cast<const float4*>(&ws[(k4 * 4 + kk) * H1]);
#pragma unroll
            for (int j = 0; j < H1 / 4; ++j) {
                float4 wv = wr[j];
                acc[j].x += xk * wv.x;
                acc[j].y += xk * wv.y;
                acc[j].z += xk * wv.z;
                acc[j].w += xk * wv.w;
            }
        }
    }
    float4* op = reinterpret_cast<float4*>(out + (size_t)row * H1);
#pragma unroll
    for (int j = 0; j < H1 / 4; ++j) op[j] = acc[j];
}

// ------------- GEMM2: relu(h1)[N,64] @ W2[64,32] -> out[N,32] --------------
__global__ __launch_bounds__(256) void gemm_h1w2(
    const float* __restrict__ Hin, const float* __restrict__ W2,
    float* __restrict__ out)
{
    __shared__ float ws[H1 * H2];                      // 8 KiB
    for (int i = threadIdx.x; i < H1 * H2; i += 256) ws[i] = W2[i];
    __syncthreads();

    int row = blockIdx.x * 256 + threadIdx.x;
    if (row >= N_NODES) return;

    const float4* xr = reinterpret_cast<const float4*>(Hin + (size_t)row * H1);
    float4 acc[H2 / 4];
#pragma unroll
    for (int j = 0; j < H2 / 4; ++j) acc[j] = make_float4(0.f, 0.f, 0.f, 0.f);

    for (int k4 = 0; k4 < H1 / 4; ++k4) {
        float4 xv = xr[k4];
        // fused relu on the h1 operand
        xv.x = fmaxf(xv.x, 0.f); xv.y = fmaxf(xv.y, 0.f);
        xv.z = fmaxf(xv.z, 0.f); xv.w = fmaxf(xv.w, 0.f);
#pragma unroll
        for (int kk = 0; kk < 4; ++kk) {
            float xk = (kk == 0) ? xv.x : (kk == 1) ? xv.y : (kk == 2) ? xv.z : xv.w;
            const float4* wr = reinterpret_cast<const float4*>(&ws[(k4 * 4 + kk) * H2]);
#pragma unroll
            for (int j = 0; j < H2 / 4; ++j) {
                float4 wv = wr[j];
                acc[j].x += xk * wv.x;
                acc[j].y += xk * wv.y;
                acc[j].z += xk * wv.z;
                acc[j].w += xk * wv.w;
            }
        }
    }
    float4* op = reinterpret_cast<float4*>(out + (size_t)row * H2);
#pragma unroll
    for (int j = 0; j < H2 / 4; ++j) op[j] = acc[j];
}

// ---------------- SpMM scatter: out[dst] += w * xin[src], D feats ----------
// One (edge, feature) pair per work-item; D=64 -> one wave per edge,
// D=32 -> two edges per wave. Row gathers fully coalesced; HW f32 atomics.
template <int D>
__global__ __launch_bounds__(256) void spmm_scatter(
    const int* __restrict__ src, const int* __restrict__ dst,
    const float* __restrict__ w, const float* __restrict__ xin,
    float* __restrict__ out)
{
    constexpr int SH = (D == 64) ? 6 : 5;
    const long long total = (long long)N_EDGES * D;
    const long long stride = (long long)gridDim.x * blockDim.x;
    for (long long i = (long long)blockIdx.x * blockDim.x + threadIdx.x;
         i < total; i += stride) {
        int e = (int)(i >> SH);
        int f = (int)(i & (D - 1));
        int s = src[e];
        int d = dst[e];
        float val = w[e] * xin[(size_t)s * D + f];
        unsafeAtomicAdd(&out[(size_t)d * D + f], val);
    }
}

extern "C" void kernel_launch(void* const* d_in, const int* in_sizes, int n_in,
                              void* d_out, int out_size, void* d_ws, size_t ws_size,
                              hipStream_t stream)
{
    const float* features    = (const float*)d_in[0];   // [N, 128]
    const float* edge_weight = (const float*)d_in[1];   // [E]
    const float* W1          = (const float*)d_in[2];   // [128, 64]
    const float* W2          = (const float*)d_in[3];   // [64, 32]
    const int*   src         = (const int*)d_in[4];     // [E]
    const int*   dst         = (const int*)d_in[5];     // [E]
    float* out = (float*)d_out;                          // [N, 32]

    float* xw1  = (float*)d_ws;                          // [N, 64] 25.6 MB
    float* h1   = xw1 + (size_t)N_NODES * H1;            // [N, 64] 25.6 MB
    float* h1w2 = h1  + (size_t)N_NODES * H1;            // [N, 32] 12.8 MB

    // accumulators must start at zero every call (atomic scatter-add)
    hipMemsetAsync(h1,  0, (size_t)N_NODES * H1 * sizeof(float), stream);
    hipMemsetAsync(out, 0, (size_t)N_NODES * H2 * sizeof(float), stream);

    dim3 blk(256);
    int gemm_grid = (N_NODES + 255) / 256;

    gemm_xw1<<<gemm_grid, blk, 0, stream>>>(features, W1, xw1);
    spmm_scatter<H1><<<16384, blk, 0, stream>>>(src, dst, edge_weight, xw1, h1);
    gemm_h1w2<<<gemm_grid, blk, 0, stream>>>(h1, W2, h1w2);
    spmm_scatter<H2><<<16384, blk, 0, stream>>>(src, dst, edge_weight, h1w2, out);
}

// Round 2
// 424.483 us; speedup vs baseline: 1.3559x; 1.3559x over previous
//
#include <hip/hip_runtime.h>

// GCN encoder: out = A @ ( relu(A @ (X W1)) W2 ),  A = COO scatter (dst <- src)
// N=100000 nodes, E=1600000 edges, F_IN=128, H1=64, H2=32, all f32.
//
// Round 2: replace atomic scatter-add SpMM (write-through limited, 400MB of
// atomic writes) with per-call counting-sort CSR build + gather segment-sum.

constexpr int N_NODES = 100000;
constexpr int N_EDGES = 1600000;
constexpr int F_IN = 128;
constexpr int H1 = 64;
constexpr int H2 = 32;
constexpr int NB1 = (N_NODES + 255) / 256;   // 391 blocks for node-sized scans

// ---------------- GEMM1: X[N,128] @ W1[128,64] -> out[N,64] ----------------
__global__ __launch_bounds__(256) void gemm_xw1(
    const float* __restrict__ X, const float* __restrict__ W1,
    float* __restrict__ out)
{
    __shared__ float ws[F_IN * H1];                    // 32 KiB
    for (int i = threadIdx.x; i < F_IN * H1; i += 256) ws[i] = W1[i];
    __syncthreads();

    int row = blockIdx.x * 256 + threadIdx.x;
    if (row >= N_NODES) return;

    const float4* xr = reinterpret_cast<const float4*>(X + (size_t)row * F_IN);
    float4 acc[H1 / 4];
#pragma unroll
    for (int j = 0; j < H1 / 4; ++j) acc[j] = make_float4(0.f, 0.f, 0.f, 0.f);

    for (int k4 = 0; k4 < F_IN / 4; ++k4) {
        float4 xv = xr[k4];
#pragma unroll
        for (int kk = 0; kk < 4; ++kk) {
            float xk = (kk == 0) ? xv.x : (kk == 1) ? xv.y : (kk == 2) ? xv.z : xv.w;
            const float4* wr = reinterpret_cast<const float4*>(&ws[(k4 * 4 + kk) * H1]);
#pragma unroll
            for (int j = 0; j < H1 / 4; ++j) {
                float4 wv = wr[j];
                acc[j].x += xk * wv.x;
                acc[j].y += xk * wv.y;
                acc[j].z += xk * wv.z;
                acc[j].w += xk * wv.w;
            }
        }
    }
    float4* op = reinterpret_cast<float4*>(out + (size_t)row * H1);
#pragma unroll
    for (int j = 0; j < H1 / 4; ++j) op[j] = acc[j];
}

// ------------- GEMM2: relu(h1)[N,64] @ W2[64,32] -> out[N,32] --------------
__global__ __launch_bounds__(256) void gemm_h1w2(
    const float* __restrict__ Hin, const float* __restrict__ W2,
    float* __restrict__ out)
{
    __shared__ float ws[H1 * H2];                      // 8 KiB
    for (int i = threadIdx.x; i < H1 * H2; i += 256) ws[i] = W2[i];
    __syncthreads();

    int row = blockIdx.x * 256 + threadIdx.x;
    if (row >= N_NODES) return;

    const float4* xr = reinterpret_cast<const float4*>(Hin + (size_t)row * H1);
    float4 acc[H2 / 4];
#pragma unroll
    for (int j = 0; j < H2 / 4; ++j) acc[j] = make_float4(0.f, 0.f, 0.f, 0.f);

    for (int k4 = 0; k4 < H1 / 4; ++k4) {
        float4 xv = xr[k4];
        xv.x = fmaxf(xv.x, 0.f); xv.y = fmaxf(xv.y, 0.f);
        xv.z = fmaxf(xv.z, 0.f); xv.w = fmaxf(xv.w, 0.f);
#pragma unroll
        for (int kk = 0; kk < 4; ++kk) {
            float xk = (kk == 0) ? xv.x : (kk == 1) ? xv.y : (kk == 2) ? xv.z : xv.w;
            const float4* wr = reinterpret_cast<const float4*>(&ws[(k4 * 4 + kk) * H2]);
#pragma unroll
            for (int j = 0; j < H2 / 4; ++j) {
                float4 wv = wr[j];
                acc[j].x += xk * wv.x;
                acc[j].y += xk * wv.y;
                acc[j].z += xk * wv.z;
                acc[j].w += xk * wv.w;
            }
        }
    }
    float4* op = reinterpret_cast<float4*>(out + (size_t)row * H2);
#pragma unroll
    for (int j = 0; j < H2 / 4; ++j) op[j] = acc[j];
}

// ---------------- counting sort by dst -> CSR ------------------------------
__global__ __launch_bounds__(256) void hist_dst(
    const int* __restrict__ dst, int* __restrict__ cnt)
{
    int e = blockIdx.x * 256 + threadIdx.x;
    if (e < N_EDGES) atomicAdd(&cnt[dst[e]], 1);
}

// in-place per-block exclusive scan of cnt; block totals -> bsum
__global__ __launch_bounds__(256) void scan_block(
    int* __restrict__ cnt, int* __restrict__ bsum)
{
    __shared__ int tmp[256];
    int i = blockIdx.x * 256 + threadIdx.x;
    int v = (i < N_NODES) ? cnt[i] : 0;
    tmp[threadIdx.x] = v;
    __syncthreads();
    for (int off = 1; off < 256; off <<= 1) {
        int add = (threadIdx.x >= off) ? tmp[threadIdx.x - off] : 0;
        __syncthreads();
        tmp[threadIdx.x] += add;
        __syncthreads();
    }
    if (i < N_NODES) cnt[i] = tmp[threadIdx.x] - v;      // block-local exclusive
    if (threadIdx.x == 255) bsum[blockIdx.x] = tmp[255]; // block total
}

// exclusive scan of NB1 block totals (single block)
__global__ __launch_bounds__(512) void scan_top(int* __restrict__ bsum)
{
    __shared__ int tmp[512];
    int t = threadIdx.x;
    int v = (t < NB1) ? bsum[t] : 0;
    tmp[t] = v;
    __syncthreads();
    for (int off = 1; off < 512; off <<= 1) {
        int add = (t >= off) ? tmp[t - off] : 0;
        __syncthreads();
        tmp[t] += add;
        __syncthreads();
    }
    if (t < NB1) bsum[t] = tmp[t] - v;                   // exclusive
}

__global__ __launch_bounds__(256) void scan_add(
    const int* __restrict__ cnt_excl, const int* __restrict__ bsum,
    int* __restrict__ row_ptr, int* __restrict__ fill)
{
    int i = blockIdx.x * 256 + threadIdx.x;
    if (i < N_NODES) {
        int v = cnt_excl[i] + bsum[blockIdx.x];
        row_ptr[i] = v;
        fill[i] = v;
    }
    if (i == 0) row_ptr[N_NODES] = N_EDGES;
}

__global__ __launch_bounds__(256) void scatter_edges(
    const int* __restrict__ src, const int* __restrict__ dst,
    const float* __restrict__ w, int* __restrict__ fill,
    int* __restrict__ csr_src, float* __restrict__ csr_w)
{
    int e = blockIdx.x * 256 + threadIdx.x;
    if (e < N_EDGES) {
        int d = dst[e];
        int pos = atomicAdd(&fill[d], 1);
        csr_src[pos] = src[e];
        csr_w[pos] = w[e];
    }
}

// ---------------- CSR SpMM (gather, no atomics) ----------------------------
// D=64: one wave per node, lane = feature. Wave-uniform edge loop.
__global__ __launch_bounds__(256) void spmm_csr64(
    const int* __restrict__ row_ptr, const int* __restrict__ csr_src,
    const float* __restrict__ csr_w, const float* __restrict__ xin,
    float* __restrict__ out)
{
    int gid = blockIdx.x * 256 + threadIdx.x;   // grid covers N*64 exactly
    int node = gid >> 6;
    int f = gid & 63;
    int start = row_ptr[node], end = row_ptr[node + 1];
    float a0 = 0.f, a1 = 0.f;
    int e = start;
    for (; e + 2 <= end; e += 2) {
        int s0 = csr_src[e], s1 = csr_src[e + 1];
        float w0 = csr_w[e], w1 = csr_w[e + 1];
        a0 += w0 * xin[(size_t)s0 * 64 + f];
        a1 += w1 * xin[(size_t)s1 * 64 + f];
    }
    if (e < end) a0 += csr_w[e] * xin[(size_t)csr_src[e] * 64 + f];
    out[(size_t)node * 64 + f] = a0 + a1;
}

// D=32: one wave per node; half-waves take even/odd edges, combine via shfl.
__global__ __launch_bounds__(256) void spmm_csr32(
    const int* __restrict__ row_ptr, const int* __restrict__ csr_src,
    const float* __restrict__ csr_w, const float* __restrict__ xin,
    float* __restrict__ out)
{
    int gid = blockIdx.x * 256 + threadIdx.x;   // grid covers N*64 exactly
    int node = gid >> 6;
    int f = gid & 31;
    int par = (gid >> 5) & 1;
    int start = row_ptr[node], end = row_ptr[node + 1];
    float acc = 0.f;
    for (int e = start + par; e < end; e += 2)
        acc += csr_w[e] * xin[(size_t)csr_src[e] * 32 + f];
    acc += __shfl_xor(acc, 32);
    if (par == 0) out[(size_t)node * 32 + f] = acc;
}

extern "C" void kernel_launch(void* const* d_in, const int* in_sizes, int n_in,
                              void* d_out, int out_size, void* d_ws, size_t ws_size,
                              hipStream_t stream)
{
    const float* features    = (const float*)d_in[0];   // [N, 128]
    const float* edge_weight = (const float*)d_in[1];   // [E]
    const float* W1          = (const float*)d_in[2];   // [128, 64]
    const float* W2          = (const float*)d_in[3];   // [64, 32]
    const int*   src         = (const int*)d_in[4];     // [E]
    const int*   dst         = (const int*)d_in[5];     // [E]
    float* out = (float*)d_out;                          // [N, 32]

    // workspace layout (bytes): all 16B-aligned
    char* p = (char*)d_ws;
    float* xw1     = (float*)p;                 p += (size_t)N_NODES * H1 * 4;  // 25.6MB
    float* h1      = (float*)p;                 p += (size_t)N_NODES * H1 * 4;  // 25.6MB
    float* csr_w   = (float*)p;                 p += (size_t)N_EDGES * 4;       // 6.4MB
    int*   csr_src = (int*)p;                   p += (size_t)N_EDGES * 4;       // 6.4MB
    int*   cnt     = (int*)p;                   p += (size_t)N_NODES * 4;
    int*   row_ptr = (int*)p;                   p += (size_t)(N_NODES + 1) * 4;
    int*   fill    = (int*)p;                   p += (size_t)N_NODES * 4;
    int*   bsum    = (int*)p;                   p += 512 * 4;
    float* h1w2    = xw1;                       // xw1 dead after spmm64; reuse

    dim3 blk(256);
    int edge_grid = (N_EDGES + 255) / 256;      // 6250
    int gemm_grid = (N_NODES + 255) / 256;      // 391

    // --- CSR build (used by both layers) ---
    hipMemsetAsync(cnt, 0, (size_t)N_NODES * 4, stream);
    hist_dst<<<edge_grid, blk, 0, stream>>>(dst, cnt);
    scan_block<<<NB1, blk, 0, stream>>>(cnt, bsum);
    scan_top<<<1, 512, 0, stream>>>(bsum);
    scan_add<<<NB1, blk, 0, stream>>>(cnt, bsum, row_ptr, fill);
    scatter_edges<<<edge_grid, blk, 0, stream>>>(src, dst, edge_weight, fill,
                                                 csr_src, csr_w);

    // --- layer 1 ---
    gemm_xw1<<<gemm_grid, blk, 0, stream>>>(features, W1, xw1);
    spmm_csr64<<<(N_NODES * 64) / 256, blk, 0, stream>>>(row_ptr, csr_src, csr_w,
                                                         xw1, h1);
    // --- layer 2 ---
    gemm_h1w2<<<gemm_grid, blk, 0, stream>>>(h1, W2, h1w2);
    spmm_csr32<<<(N_NODES * 64) / 256, blk, 0, stream>>>(row_ptr, csr_src, csr_w,
                                                         h1w2, out);
}

// Round 3
// 392.487 us; speedup vs baseline: 1.4665x; 1.0815x over previous
//
#include <hip/hip_runtime.h>

// GCN encoder: out = A @ ( relu(A @ (X W1)) W2 ),  A = COO scatter (dst <- src)
// N=100000 nodes, E=1600000 edges, F_IN=128, H1=64, H2=32, all f32.
//
// Round 3: pack CSR entry into int2 (one 8B store per edge in scatter: one
// dirty line instead of two) + 4-way unrolled gather loops in the SpMMs.

constexpr int N_NODES = 100000;
constexpr int N_EDGES = 1600000;
constexpr int F_IN = 128;
constexpr int H1 = 64;
constexpr int H2 = 32;
constexpr int NB1 = (N_NODES + 255) / 256;   // 391 blocks for node-sized scans

// ---------------- GEMM1: X[N,128] @ W1[128,64] -> out[N,64] ----------------
__global__ __launch_bounds__(256) void gemm_xw1(
    const float* __restrict__ X, const float* __restrict__ W1,
    float* __restrict__ out)
{
    __shared__ float ws[F_IN * H1];                    // 32 KiB
    for (int i = threadIdx.x; i < F_IN * H1; i += 256) ws[i] = W1[i];
    __syncthreads();

    int row = blockIdx.x * 256 + threadIdx.x;
    if (row >= N_NODES) return;

    const float4* xr = reinterpret_cast<const float4*>(X + (size_t)row * F_IN);
    float4 acc[H1 / 4];
#pragma unroll
    for (int j = 0; j < H1 / 4; ++j) acc[j] = make_float4(0.f, 0.f, 0.f, 0.f);

    for (int k4 = 0; k4 < F_IN / 4; ++k4) {
        float4 xv = xr[k4];
#pragma unroll
        for (int kk = 0; kk < 4; ++kk) {
            float xk = (kk == 0) ? xv.x : (kk == 1) ? xv.y : (kk == 2) ? xv.z : xv.w;
            const float4* wr = reinterpret_cast<const float4*>(&ws[(k4 * 4 + kk) * H1]);
#pragma unroll
            for (int j = 0; j < H1 / 4; ++j) {
                float4 wv = wr[j];
                acc[j].x += xk * wv.x;
                acc[j].y += xk * wv.y;
                acc[j].z += xk * wv.z;
                acc[j].w += xk * wv.w;
            }
        }
    }
    float4* op = reinterpret_cast<float4*>(out + (size_t)row * H1);
#pragma unroll
    for (int j = 0; j < H1 / 4; ++j) op[j] = acc[j];
}

// ------------- GEMM2: relu(h1)[N,64] @ W2[64,32] -> out[N,32] --------------
__global__ __launch_bounds__(256) void gemm_h1w2(
    const float* __restrict__ Hin, const float* __restrict__ W2,
    float* __restrict__ out)
{
    __shared__ float ws[H1 * H2];                      // 8 KiB
    for (int i = threadIdx.x; i < H1 * H2; i += 256) ws[i] = W2[i];
    __syncthreads();

    int row = blockIdx.x * 256 + threadIdx.x;
    if (row >= N_NODES) return;

    const float4* xr = reinterpret_cast<const float4*>(Hin + (size_t)row * H1);
    float4 acc[H2 / 4];
#pragma unroll
    for (int j = 0; j < H2 / 4; ++j) acc[j] = make_float4(0.f, 0.f, 0.f, 0.f);

    for (int k4 = 0; k4 < H1 / 4; ++k4) {
        float4 xv = xr[k4];
        xv.x = fmaxf(xv.x, 0.f); xv.y = fmaxf(xv.y, 0.f);
        xv.z = fmaxf(xv.z, 0.f); xv.w = fmaxf(xv.w, 0.f);
#pragma unroll
        for (int kk = 0; kk < 4; ++kk) {
            float xk = (kk == 0) ? xv.x : (kk == 1) ? xv.y : (kk == 2) ? xv.z : xv.w;
            const float4* wr = reinterpret_cast<const float4*>(&ws[(k4 * 4 + kk) * H2]);
#pragma unroll
            for (int j = 0; j < H2 / 4; ++j) {
                float4 wv = wr[j];
                acc[j].x += xk * wv.x;
                acc[j].y += xk * wv.y;
                acc[j].z += xk * wv.z;
                acc[j].w += xk * wv.w;
            }
        }
    }
    float4* op = reinterpret_cast<float4*>(out + (size_t)row * H2);
#pragma unroll
    for (int j = 0; j < H2 / 4; ++j) op[j] = acc[j];
}

// ---------------- counting sort by dst -> CSR (packed int2) ----------------
__global__ __launch_bounds__(256) void hist_dst(
    const int* __restrict__ dst, int* __restrict__ cnt)
{
    int e = blockIdx.x * 256 + threadIdx.x;
    if (e < N_EDGES) atomicAdd(&cnt[dst[e]], 1);
}

__global__ __launch_bounds__(256) void scan_block(
    int* __restrict__ cnt, int* __restrict__ bsum)
{
    __shared__ int tmp[256];
    int i = blockIdx.x * 256 + threadIdx.x;
    int v = (i < N_NODES) ? cnt[i] : 0;
    tmp[threadIdx.x] = v;
    __syncthreads();
    for (int off = 1; off < 256; off <<= 1) {
        int add = (threadIdx.x >= off) ? tmp[threadIdx.x - off] : 0;
        __syncthreads();
        tmp[threadIdx.x] += add;
        __syncthreads();
    }
    if (i < N_NODES) cnt[i] = tmp[threadIdx.x] - v;      // block-local exclusive
    if (threadIdx.x == 255) bsum[blockIdx.x] = tmp[255]; // block total
}

__global__ __launch_bounds__(512) void scan_top(int* __restrict__ bsum)
{
    __shared__ int tmp[512];
    int t = threadIdx.x;
    int v = (t < NB1) ? bsum[t] : 0;
    tmp[t] = v;
    __syncthreads();
    for (int off = 1; off < 512; off <<= 1) {
        int add = (t >= off) ? tmp[t - off] : 0;
        __syncthreads();
        tmp[t] += add;
        __syncthreads();
    }
    if (t < NB1) bsum[t] = tmp[t] - v;                   // exclusive
}

__global__ __launch_bounds__(256) void scan_add(
    const int* __restrict__ cnt_excl, const int* __restrict__ bsum,
    int* __restrict__ row_ptr, int* __restrict__ fill)
{
    int i = blockIdx.x * 256 + threadIdx.x;
    if (i < N_NODES) {
        int v = cnt_excl[i] + bsum[blockIdx.x];
        row_ptr[i] = v;
        fill[i] = v;
    }
    if (i == 0) row_ptr[N_NODES] = N_EDGES;
}

__global__ __launch_bounds__(256) void scatter_edges(
    const int* __restrict__ src, const int* __restrict__ dst,
    const float* __restrict__ w, int* __restrict__ fill,
    int2* __restrict__ csr)          // .x = src node, .y = weight bits
{
    int e = blockIdx.x * 256 + threadIdx.x;
    if (e < N_EDGES) {
        int d = dst[e];
        int pos = atomicAdd(&fill[d], 1);
        csr[pos] = make_int2(src[e], __float_as_int(w[e]));
    }
}

// ---------------- CSR SpMM (gather, no atomics) ----------------------------
// D=64: one wave per node, lane = feature; wave-uniform edge loop, 4-way ILP.
__global__ __launch_bounds__(256) void spmm_csr64(
    const int* __restrict__ row_ptr, const int2* __restrict__ csr,
    const float* __restrict__ xin, float* __restrict__ out)
{
    int gid = blockIdx.x * 256 + threadIdx.x;   // grid covers N*64 exactly
    int node = gid >> 6;
    int f = gid & 63;
    int start = row_ptr[node], end = row_ptr[node + 1];
    float a0 = 0.f, a1 = 0.f, a2 = 0.f, a3 = 0.f;
    int e = start;
    for (; e + 4 <= end; e += 4) {
        int2 c0 = csr[e], c1 = csr[e + 1], c2 = csr[e + 2], c3 = csr[e + 3];
        a0 += __int_as_float(c0.y) * xin[(size_t)c0.x * 64 + f];
        a1 += __int_as_float(c1.y) * xin[(size_t)c1.x * 64 + f];
        a2 += __int_as_float(c2.y) * xin[(size_t)c2.x * 64 + f];
        a3 += __int_as_float(c3.y) * xin[(size_t)c3.x * 64 + f];
    }
    for (; e < end; ++e) {
        int2 c = csr[e];
        a0 += __int_as_float(c.y) * xin[(size_t)c.x * 64 + f];
    }
    out[(size_t)node * 64 + f] = (a0 + a1) + (a2 + a3);
}

// D=32: one wave per node; half-waves take even/odd edges, combine via shfl.
__global__ __launch_bounds__(256) void spmm_csr32(
    const int* __restrict__ row_ptr, const int2* __restrict__ csr,
    const float* __restrict__ xin, float* __restrict__ out)
{
    int gid = blockIdx.x * 256 + threadIdx.x;   // grid covers N*64 exactly
    int node = gid >> 6;
    int f = gid & 31;
    int par = (gid >> 5) & 1;
    int start = row_ptr[node], end = row_ptr[node + 1];
    float a0 = 0.f, a1 = 0.f;
    int e = start + par;
    for (; e + 3 < end; e += 4) {               // this parity: e and e+2
        int2 c0 = csr[e], c1 = csr[e + 2];
        a0 += __int_as_float(c0.y) * xin[(size_t)c0.x * 32 + f];
        a1 += __int_as_float(c1.y) * xin[(size_t)c1.x * 32 + f];
    }
    for (; e < end; e += 2) {
        int2 c = csr[e];
        a0 += __int_as_float(c.y) * xin[(size_t)c.x * 32 + f];
    }
    float acc = a0 + a1;
    acc += __shfl_xor(acc, 32);
    if (par == 0) out[(size_t)node * 32 + f] = acc;
}

extern "C" void kernel_launch(void* const* d_in, const int* in_sizes, int n_in,
                              void* d_out, int out_size, void* d_ws, size_t ws_size,
                              hipStream_t stream)
{
    const float* features    = (const float*)d_in[0];   // [N, 128]
    const float* edge_weight = (const float*)d_in[1];   // [E]
    const float* W1          = (const float*)d_in[2];   // [128, 64]
    const float* W2          = (const float*)d_in[3];   // [64, 32]
    const int*   src         = (const int*)d_in[4];     // [E]
    const int*   dst         = (const int*)d_in[5];     // [E]
    float* out = (float*)d_out;                          // [N, 32]

    // workspace layout (bytes): all 16B-aligned
    char* p = (char*)d_ws;
    float* xw1     = (float*)p;                 p += (size_t)N_NODES * H1 * 4;  // 25.6MB
    float* h1      = (float*)p;                 p += (size_t)N_NODES * H1 * 4;  // 25.6MB
    int2*  csr     = (int2*)p;                  p += (size_t)N_EDGES * 8;       // 12.8MB
    int*   cnt     = (int*)p;                   p += (size_t)N_NODES * 4;
    int*   row_ptr = (int*)p;                   p += (size_t)(N_NODES + 1) * 4;
    int*   fill    = (int*)p;                   p += (size_t)N_NODES * 4;
    int*   bsum    = (int*)p;                   p += 512 * 4;
    float* h1w2    = xw1;                       // xw1 dead after spmm64; reuse

    dim3 blk(256);
    int edge_grid = (N_EDGES + 255) / 256;      // 6250
    int gemm_grid = (N_NODES + 255) / 256;      // 391

    // --- CSR build (used by both layers) ---
    hipMemsetAsync(cnt, 0, (size_t)N_NODES * 4, stream);
    hist_dst<<<edge_grid, blk, 0, stream>>>(dst, cnt);
    scan_block<<<NB1, blk, 0, stream>>>(cnt, bsum);
    scan_top<<<1, 512, 0, stream>>>(bsum);
    scan_add<<<NB1, blk, 0, stream>>>(cnt, bsum, row_ptr, fill);
    scatter_edges<<<edge_grid, blk, 0, stream>>>(src, dst, edge_weight, fill, csr);

    // --- layer 1 ---
    gemm_xw1<<<gemm_grid, blk, 0, stream>>>(features, W1, xw1);
    spmm_csr64<<<(N_NODES * 64) / 256, blk, 0, stream>>>(row_ptr, csr, xw1, h1);
    // --- layer 2 ---
    gemm_h1w2<<<gemm_grid, blk, 0, stream>>>(h1, W2, h1w2);
    spmm_csr32<<<(N_NODES * 64) / 256, blk, 0, stream>>>(row_ptr, csr, h1w2, out);
}

// Round 4
// 335.614 us; speedup vs baseline: 1.7150x; 1.1695x over previous
//
#include <hip/hip_runtime.h>

// GCN encoder: out = A @ ( relu(A @ (X W1)) W2 ),  A = COO scatter (dst <- src)
// N=100000 nodes, E=1600000 edges, F_IN=128, H1=64, H2=32, all f32.
//
// Round 4: two-pass binned counting sort. Pass1 bins edges by dst>>10 into 98
// buckets (staging ranges == final CSR segment ranges, so no extra histogram);
// pass2 does the per-node scatter with LDS fill counters inside a 131KB
// L2-resident window. gemm_xw1 fused into pass1's grid (independent work).

constexpr int N_NODES = 100000;
constexpr int N_EDGES = 1600000;
constexpr int F_IN = 128;
constexpr int H1 = 64;
constexpr int H2 = 32;
constexpr int NB1 = (N_NODES + 255) / 256;     // 391 node-scan blocks
constexpr int BSHIFT = 10;                     // 1024 nodes per bucket
constexpr int NBUCK = (N_NODES + 1023) / 1024; // 98 buckets
constexpr int CHUNK = 2048;                    // edges per pass1 workgroup
constexpr int P1_WGS = (N_EDGES + CHUNK - 1) / CHUNK;  // 782
constexpr int GEMM_WGS = (N_NODES + 255) / 256;        // 391

// ---------------- counting-sort front end ----------------------------------
__global__ __launch_bounds__(256) void hist_dst(
    const int* __restrict__ dst, int* __restrict__ cnt)
{
    int e = blockIdx.x * 256 + threadIdx.x;
    if (e < N_EDGES) atomicAdd(&cnt[dst[e]], 1);
}

__global__ __launch_bounds__(256) void scan_block(
    int* __restrict__ cnt, int* __restrict__ bsum)
{
    __shared__ int tmp[256];
    int i = blockIdx.x * 256 + threadIdx.x;
    int v = (i < N_NODES) ? cnt[i] : 0;
    tmp[threadIdx.x] = v;
    __syncthreads();
    for (int off = 1; off < 256; off <<= 1) {
        int add = (threadIdx.x >= off) ? tmp[threadIdx.x - off] : 0;
        __syncthreads();
        tmp[threadIdx.x] += add;
        __syncthreads();
    }
    if (i < N_NODES) cnt[i] = tmp[threadIdx.x] - v;      // block-local exclusive
    if (threadIdx.x == 255) bsum[blockIdx.x] = tmp[255]; // block total
}

__global__ __launch_bounds__(512) void scan_top(int* __restrict__ bsum)
{
    __shared__ int tmp[512];
    int t = threadIdx.x;
    int v = (t < NB1) ? bsum[t] : 0;
    tmp[t] = v;
    __syncthreads();
    for (int off = 1; off < 512; off <<= 1) {
        int add = (t >= off) ? tmp[t - off] : 0;
        __syncthreads();
        tmp[t] += add;
        __syncthreads();
    }
    if (t < NB1) bsum[t] = tmp[t] - v;                   // exclusive
}

// row_ptr + per-bucket fill pointers (bucket base == row_ptr at 1024-multiples)
__global__ __launch_bounds__(256) void scan_add(
    const int* __restrict__ cnt_excl, const int* __restrict__ bsum,
    int* __restrict__ row_ptr, int* __restrict__ bucket_fill)
{
    int i = blockIdx.x * 256 + threadIdx.x;
    if (i < N_NODES) {
        int v = cnt_excl[i] + bsum[blockIdx.x];
        row_ptr[i] = v;
        if ((i & 1023) == 0) bucket_fill[i >> BSHIFT] = v;
    }
    if (i == 0) row_ptr[N_NODES] = N_EDGES;
}

// ---- pass1: bin edges by dst>>10 into staging (+ fused gemm_xw1 blocks) ----
// staging record: .x = src | (dst_low10 << 17)   (src < 2^17), .y = w bits
__global__ __launch_bounds__(256) void pass1_bin_gemm1(
    const int* __restrict__ src, const int* __restrict__ dst,
    const float* __restrict__ w, int* __restrict__ bucket_fill,
    int2* __restrict__ staging,
    const float* __restrict__ X, const float* __restrict__ W1,
    float* __restrict__ xw1out)
{
    __shared__ float smem[F_IN * H1];                    // 32 KiB, shared by both roles

    if (blockIdx.x >= P1_WGS) {
        // ---------------- gemm_xw1 role ----------------
        for (int i = threadIdx.x; i < F_IN * H1; i += 256) smem[i] = W1[i];
        __syncthreads();
        int row = (blockIdx.x - P1_WGS) * 256 + threadIdx.x;
        if (row >= N_NODES) return;
        const float4* xr = reinterpret_cast<const float4*>(X + (size_t)row * F_IN);
        float4 acc[H1 / 4];
#pragma unroll
        for (int j = 0; j < H1 / 4; ++j) acc[j] = make_float4(0.f, 0.f, 0.f, 0.f);
        for (int k4 = 0; k4 < F_IN / 4; ++k4) {
            float4 xv = xr[k4];
#pragma unroll
            for (int kk = 0; kk < 4; ++kk) {
                float xk = (kk == 0) ? xv.x : (kk == 1) ? xv.y : (kk == 2) ? xv.z : xv.w;
                const float4* wr = reinterpret_cast<const float4*>(&smem[(k4 * 4 + kk) * H1]);
#pragma unroll
                for (int j = 0; j < H1 / 4; ++j) {
                    float4 wv = wr[j];
                    acc[j].x += xk * wv.x;
                    acc[j].y += xk * wv.y;
                    acc[j].z += xk * wv.z;
                    acc[j].w += xk * wv.w;
                }
            }
        }
        float4* op = reinterpret_cast<float4*>(xw1out + (size_t)row * H1);
#pragma unroll
        for (int j = 0; j < H1 / 4; ++j) op[j] = acc[j];
        return;
    }

    // ---------------- binning role ----------------
    int* lcnt  = (int*)smem;        // [128] counters, then reused as cursors
    int* lbase = lcnt + 128;        // [128] reserved global bases

    int e0 = blockIdx.x * CHUNK;
    int nhere = N_EDGES - e0; if (nhere > CHUNK) nhere = CHUNK;

    if (threadIdx.x < 128) lcnt[threadIdx.x] = 0;
    __syncthreads();

    int   es[CHUNK / 256];
    int   ed[CHUNK / 256];
    float ew[CHUNK / 256];
#pragma unroll
    for (int k = 0; k < CHUNK / 256; ++k) {
        int local = k * 256 + threadIdx.x;
        bool v = local < nhere;
        int idx = e0 + local;
        es[k] = v ? src[idx] : 0;
        ed[k] = v ? dst[idx] : -1;
        ew[k] = v ? w[idx] : 0.f;
        if (v) atomicAdd(&lcnt[ed[k] >> BSHIFT], 1);
    }
    __syncthreads();
    if (threadIdx.x < NBUCK) {
        int c = lcnt[threadIdx.x];
        lbase[threadIdx.x] = (c > 0) ? atomicAdd(&bucket_fill[threadIdx.x], c) : 0;
    }
    __syncthreads();
    if (threadIdx.x < 128) lcnt[threadIdx.x] = 0;        // reuse as cursors
    __syncthreads();
#pragma unroll
    for (int k = 0; k < CHUNK / 256; ++k) {
        if (ed[k] >= 0) {
            int b = ed[k] >> BSHIFT;
            int r = atomicAdd(&lcnt[b], 1);
            staging[lbase[b] + r] =
                make_int2(es[k] | ((ed[k] & 1023) << 17), __float_as_int(ew[k]));
        }
    }
}

// ---- pass2: per-bucket scatter with LDS fill counters (L2-local window) ----
__global__ __launch_bounds__(1024) void pass2_scatter(
    const int* __restrict__ row_ptr, const int2* __restrict__ staging,
    int2* __restrict__ csr)
{
    __shared__ int lfill[1024];
    int nb = blockIdx.x << BSHIFT;
    int t = threadIdx.x;
    int node = nb + t;
    lfill[t] = (node < N_NODES) ? row_ptr[node] : 0;
    __syncthreads();

    int start = row_ptr[nb];
    int endn = nb + 1024; if (endn > N_NODES) endn = N_NODES;
    int end = row_ptr[endn];
    for (int e = start + t; e < end; e += 1024) {
        int2 c = staging[e];
        int dlow = (c.x >> 17) & 1023;
        int pos = atomicAdd(&lfill[dlow], 1);
        csr[pos] = make_int2(c.x & 0x1FFFF, c.y);
    }
}

// ------------- GEMM2: relu(h1)[N,64] @ W2[64,32] -> out[N,32] --------------
__global__ __launch_bounds__(256) void gemm_h1w2(
    const float* __restrict__ Hin, const float* __restrict__ W2,
    float* __restrict__ out)
{
    __shared__ float ws[H1 * H2];                      // 8 KiB
    for (int i = threadIdx.x; i < H1 * H2; i += 256) ws[i] = W2[i];
    __syncthreads();

    int row = blockIdx.x * 256 + threadIdx.x;
    if (row >= N_NODES) return;

    const float4* xr = reinterpret_cast<const float4*>(Hin + (size_t)row * H1);
    float4 acc[H2 / 4];
#pragma unroll
    for (int j = 0; j < H2 / 4; ++j) acc[j] = make_float4(0.f, 0.f, 0.f, 0.f);

    for (int k4 = 0; k4 < H1 / 4; ++k4) {
        float4 xv = xr[k4];
        xv.x = fmaxf(xv.x, 0.f); xv.y = fmaxf(xv.y, 0.f);
        xv.z = fmaxf(xv.z, 0.f); xv.w = fmaxf(xv.w, 0.f);
#pragma unroll
        for (int kk = 0; kk < 4; ++kk) {
            float xk = (kk == 0) ? xv.x : (kk == 1) ? xv.y : (kk == 2) ? xv.z : xv.w;
            const float4* wr = reinterpret_cast<const float4*>(&ws[(k4 * 4 + kk) * H2]);
#pragma unroll
            for (int j = 0; j < H2 / 4; ++j) {
                float4 wv = wr[j];
                acc[j].x += xk * wv.x;
                acc[j].y += xk * wv.y;
                acc[j].z += xk * wv.z;
                acc[j].w += xk * wv.w;
            }
        }
    }
    float4* op = reinterpret_cast<float4*>(out + (size_t)row * H2);
#pragma unroll
    for (int j = 0; j < H2 / 4; ++j) op[j] = acc[j];
}

// ---------------- CSR SpMM (gather, no atomics) ----------------------------
__global__ __launch_bounds__(256) void spmm_csr64(
    const int* __restrict__ row_ptr, const int2* __restrict__ csr,
    const float* __restrict__ xin, float* __restrict__ out)
{
    int gid = blockIdx.x * 256 + threadIdx.x;   // grid covers N*64 exactly
    int node = gid >> 6;
    int f = gid & 63;
    int start = row_ptr[node], end = row_ptr[node + 1];
    float a0 = 0.f, a1 = 0.f, a2 = 0.f, a3 = 0.f;
    int e = start;
    for (; e + 4 <= end; e += 4) {
        int2 c0 = csr[e], c1 = csr[e + 1], c2 = csr[e + 2], c3 = csr[e + 3];
        a0 += __int_as_float(c0.y) * xin[(size_t)c0.x * 64 + f];
        a1 += __int_as_float(c1.y) * xin[(size_t)c1.x * 64 + f];
        a2 += __int_as_float(c2.y) * xin[(size_t)c2.x * 64 + f];
        a3 += __int_as_float(c3.y) * xin[(size_t)c3.x * 64 + f];
    }
    for (; e < end; ++e) {
        int2 c = csr[e];
        a0 += __int_as_float(c.y) * xin[(size_t)c.x * 64 + f];
    }
    out[(size_t)node * 64 + f] = (a0 + a1) + (a2 + a3);
}

__global__ __launch_bounds__(256) void spmm_csr32(
    const int* __restrict__ row_ptr, const int2* __restrict__ csr,
    const float* __restrict__ xin, float* __restrict__ out)
{
    int gid = blockIdx.x * 256 + threadIdx.x;   // grid covers N*64 exactly
    int node = gid >> 6;
    int f = gid & 31;
    int par = (gid >> 5) & 1;
    int start = row_ptr[node], end = row_ptr[node + 1];
    float a0 = 0.f, a1 = 0.f;
    int e = start + par;
    for (; e + 3 < end; e += 4) {               // this parity: e and e+2
        int2 c0 = csr[e], c1 = csr[e + 2];
        a0 += __int_as_float(c0.y) * xin[(size_t)c0.x * 32 + f];
        a1 += __int_as_float(c1.y) * xin[(size_t)c1.x * 32 + f];
    }
    for (; e < end; e += 2) {
        int2 c = csr[e];
        a0 += __int_as_float(c.y) * xin[(size_t)c.x * 32 + f];
    }
    float acc = a0 + a1;
    acc += __shfl_xor(acc, 32);
    if (par == 0) out[(size_t)node * 32 + f] = acc;
}

extern "C" void kernel_launch(void* const* d_in, const int* in_sizes, int n_in,
                              void* d_out, int out_size, void* d_ws, size_t ws_size,
                              hipStream_t stream)
{
    const float* features    = (const float*)d_in[0];   // [N, 128]
    const float* edge_weight = (const float*)d_in[1];   // [E]
    const float* W1          = (const float*)d_in[2];   // [128, 64]
    const float* W2          = (const float*)d_in[3];   // [64, 32]
    const int*   src         = (const int*)d_in[4];     // [E]
    const int*   dst         = (const int*)d_in[5];     // [E]
    float* out = (float*)d_out;                          // [N, 32]

    // workspace layout; staging aliases h1 (disjoint lifetimes:
    // staging live pass1->pass2, h1 live spmm64->gemm2)
    char* p = (char*)d_ws;
    float* xw1      = (float*)p;                p += (size_t)N_NODES * H1 * 4;  // 25.6MB
    float* h1       = (float*)p;                p += (size_t)N_NODES * H1 * 4;  // 25.6MB
    int2*  csr      = (int2*)p;                 p += (size_t)N_EDGES * 8;       // 12.8MB
    int*   cnt      = (int*)p;                  p += (size_t)N_NODES * 4;
    int*   row_ptr  = (int*)p;                  p += (size_t)(N_NODES + 1) * 4;
    int*   bsum     = (int*)p;                  p += 512 * 4;
    int*   bucket_fill = (int*)p;               p += 128 * 4;
    int2*  staging  = (int2*)h1;
    float* h1w2     = xw1;                      // xw1 dead after spmm64; reuse

    dim3 blk(256);
    int edge_grid = (N_EDGES + 255) / 256;      // 6250

    // --- CSR build (used by both layers); gemm1 fused into pass1 grid ---
    hipMemsetAsync(cnt, 0, (size_t)N_NODES * 4, stream);
    hist_dst<<<edge_grid, blk, 0, stream>>>(dst, cnt);
    scan_block<<<NB1, blk, 0, stream>>>(cnt, bsum);
    scan_top<<<1, 512, 0, stream>>>(bsum);
    scan_add<<<NB1, blk, 0, stream>>>(cnt, bsum, row_ptr, bucket_fill);
    pass1_bin_gemm1<<<P1_WGS + GEMM_WGS, blk, 0, stream>>>(
        src, dst, edge_weight, bucket_fill, staging, features, W1, xw1);
    pass2_scatter<<<NBUCK, 1024, 0, stream>>>(row_ptr, staging, csr);

    // --- layer 1 aggregate ---
    spmm_csr64<<<(N_NODES * 64) / 256, blk, 0, stream>>>(row_ptr, csr, xw1, h1);
    // --- layer 2 ---
    gemm_h1w2<<<GEMM_WGS, blk, 0, stream>>>(h1, W2, h1w2);
    spmm_csr32<<<(N_NODES * 64) / 256, blk, 0, stream>>>(row_ptr, csr, h1w2, out);
}

// Round 5
// 330.987 us; speedup vs baseline: 1.7389x; 1.0140x over previous
//
#include <hip/hip_runtime.h>
#include <hip/hip_fp16.h>

// GCN encoder: out = A @ ( relu(A @ (X W1)) W2 ),  A = COO scatter (dst <- src)
// N=100000 nodes, E=1600000 edges, F_IN=128, H1=64, H2=32, all f32.
//
// Round 5: (a) pass1's fused gemm tiles W1 through 8KB LDS (was 32KB) so the
// binning blocks are no longer LDS-occupancy-capped (5 -> 20 wg/CU);
// (b) SpMM gather tables (xw1, h1w2) stored fp16 -> LLC gather traffic halved.

constexpr int N_NODES = 100000;
constexpr int N_EDGES = 1600000;
constexpr int F_IN = 128;
constexpr int H1 = 64;
constexpr int H2 = 32;
constexpr int NB1 = (N_NODES + 255) / 256;     // 391 node-scan blocks
constexpr int BSHIFT = 10;                     // 1024 nodes per bucket
constexpr int NBUCK = (N_NODES + 1023) / 1024; // 98 buckets
constexpr int CHUNK = 2048;                    // edges per pass1 workgroup
constexpr int P1_WGS = (N_EDGES + CHUNK - 1) / CHUNK;  // 782
constexpr int GEMM_WGS = (N_NODES + 255) / 256;        // 391
constexpr int TILE_N = 16;                     // W1 column tile (8KB LDS)

// ---------------- counting-sort front end ----------------------------------
__global__ __launch_bounds__(256) void hist_dst(
    const int* __restrict__ dst, int* __restrict__ cnt)
{
    int e = blockIdx.x * 256 + threadIdx.x;
    if (e < N_EDGES) atomicAdd(&cnt[dst[e]], 1);
}

__global__ __launch_bounds__(256) void scan_block(
    int* __restrict__ cnt, int* __restrict__ bsum)
{
    __shared__ int tmp[256];
    int i = blockIdx.x * 256 + threadIdx.x;
    int v = (i < N_NODES) ? cnt[i] : 0;
    tmp[threadIdx.x] = v;
    __syncthreads();
    for (int off = 1; off < 256; off <<= 1) {
        int add = (threadIdx.x >= off) ? tmp[threadIdx.x - off] : 0;
        __syncthreads();
        tmp[threadIdx.x] += add;
        __syncthreads();
    }
    if (i < N_NODES) cnt[i] = tmp[threadIdx.x] - v;      // block-local exclusive
    if (threadIdx.x == 255) bsum[blockIdx.x] = tmp[255]; // block total
}

__global__ __launch_bounds__(512) void scan_top(int* __restrict__ bsum)
{
    __shared__ int tmp[512];
    int t = threadIdx.x;
    int v = (t < NB1) ? bsum[t] : 0;
    tmp[t] = v;
    __syncthreads();
    for (int off = 1; off < 512; off <<= 1) {
        int add = (t >= off) ? tmp[t - off] : 0;
        __syncthreads();
        tmp[t] += add;
        __syncthreads();
    }
    if (t < NB1) bsum[t] = tmp[t] - v;                   // exclusive
}

__global__ __launch_bounds__(256) void scan_add(
    const int* __restrict__ cnt_excl, const int* __restrict__ bsum,
    int* __restrict__ row_ptr, int* __restrict__ bucket_fill)
{
    int i = blockIdx.x * 256 + threadIdx.x;
    if (i < N_NODES) {
        int v = cnt_excl[i] + bsum[blockIdx.x];
        row_ptr[i] = v;
        if ((i & 1023) == 0) bucket_fill[i >> BSHIFT] = v;
    }
    if (i == 0) row_ptr[N_NODES] = N_EDGES;
}

// ---- pass1: bin edges by dst>>10 into staging (+ fused gemm_xw1 blocks) ----
// staging record: .x = src | (dst_low10 << 17)   (src < 2^17), .y = w bits
// gemm role writes xw1 as fp16.
__global__ __launch_bounds__(256) void pass1_bin_gemm1(
    const int* __restrict__ src, const int* __restrict__ dst,
    const float* __restrict__ w, int* __restrict__ bucket_fill,
    int2* __restrict__ staging,
    const float* __restrict__ X, const float* __restrict__ W1,
    __half* __restrict__ xw1out)
{
    __shared__ float smem[F_IN * TILE_N];                // 8 KiB (both roles)

    if (blockIdx.x >= P1_WGS) {
        // ---------------- gemm_xw1 role (tiled W1) ----------------
        int row = (blockIdx.x - P1_WGS) * 256 + threadIdx.x;
        bool alive = row < N_NODES;
        const float4* xr = alive
            ? reinterpret_cast<const float4*>(X + (size_t)row * F_IN) : nullptr;
        __half2* oh = alive
            ? reinterpret_cast<__half2*>(xw1out + (size_t)row * H1) : nullptr;

        for (int t = 0; t < H1 / TILE_N; ++t) {
            // stage W1[:, t*16 .. t*16+16) -> smem[k*16+j]
            for (int i = threadIdx.x; i < F_IN * TILE_N; i += 256) {
                int k = i >> 4, j = i & 15;
                smem[i] = W1[(size_t)k * H1 + t * TILE_N + j];
            }
            __syncthreads();
            if (alive) {
                float4 acc[TILE_N / 4];
#pragma unroll
                for (int j = 0; j < TILE_N / 4; ++j)
                    acc[j] = make_float4(0.f, 0.f, 0.f, 0.f);
                for (int k4 = 0; k4 < F_IN / 4; ++k4) {
                    float4 xv = xr[k4];
#pragma unroll
                    for (int kk = 0; kk < 4; ++kk) {
                        float xk = (kk == 0) ? xv.x : (kk == 1) ? xv.y
                                 : (kk == 2) ? xv.z : xv.w;
                        const float4* wr = reinterpret_cast<const float4*>(
                            &smem[(k4 * 4 + kk) * TILE_N]);
#pragma unroll
                        for (int j = 0; j < TILE_N / 4; ++j) {
                            float4 wv = wr[j];
                            acc[j].x += xk * wv.x;
                            acc[j].y += xk * wv.y;
                            acc[j].z += xk * wv.z;
                            acc[j].w += xk * wv.w;
                        }
                    }
                }
#pragma unroll
                for (int j = 0; j < TILE_N / 4; ++j) {
                    oh[t * (TILE_N / 2) + j * 2 + 0] =
                        __floats2half2_rn(acc[j].x, acc[j].y);
                    oh[t * (TILE_N / 2) + j * 2 + 1] =
                        __floats2half2_rn(acc[j].z, acc[j].w);
                }
            }
            __syncthreads();
        }
        return;
    }

    // ---------------- binning role ----------------
    int* lcnt  = (int*)smem;        // [128] counters, then reused as cursors
    int* lbase = lcnt + 128;        // [128] reserved global bases

    int e0 = blockIdx.x * CHUNK;
    int nhere = N_EDGES - e0; if (nhere > CHUNK) nhere = CHUNK;

    if (threadIdx.x < 128) lcnt[threadIdx.x] = 0;
    __syncthreads();

    int   es[CHUNK / 256];
    int   ed[CHUNK / 256];
    float ew[CHUNK / 256];
#pragma unroll
    for (int k = 0; k < CHUNK / 256; ++k) {
        int local = k * 256 + threadIdx.x;
        bool v = local < nhere;
        int idx = e0 + local;
        es[k] = v ? src[idx] : 0;
        ed[k] = v ? dst[idx] : -1;
        ew[k] = v ? w[idx] : 0.f;
        if (v) atomicAdd(&lcnt[ed[k] >> BSHIFT], 1);
    }
    __syncthreads();
    if (threadIdx.x < NBUCK) {
        int c = lcnt[threadIdx.x];
        lbase[threadIdx.x] = (c > 0) ? atomicAdd(&bucket_fill[threadIdx.x], c) : 0;
    }
    __syncthreads();
    if (threadIdx.x < 128) lcnt[threadIdx.x] = 0;        // reuse as cursors
    __syncthreads();
#pragma unroll
    for (int k = 0; k < CHUNK / 256; ++k) {
        if (ed[k] >= 0) {
            int b = ed[k] >> BSHIFT;
            int r = atomicAdd(&lcnt[b], 1);
            staging[lbase[b] + r] =
                make_int2(es[k] | ((ed[k] & 1023) << 17), __float_as_int(ew[k]));
        }
    }
}

// ---- pass2: per-bucket scatter with LDS fill counters (L2-local window) ----
__global__ __launch_bounds__(1024) void pass2_scatter(
    const int* __restrict__ row_ptr, const int2* __restrict__ staging,
    int2* __restrict__ csr)
{
    __shared__ int lfill[1024];
    int nb = blockIdx.x << BSHIFT;
    int t = threadIdx.x;
    int node = nb + t;
    lfill[t] = (node < N_NODES) ? row_ptr[node] : 0;
    __syncthreads();

    int start = row_ptr[nb];
    int endn = nb + 1024; if (endn > N_NODES) endn = N_NODES;
    int end = row_ptr[endn];
    for (int e = start + t; e < end; e += 1024) {
        int2 c = staging[e];
        int dlow = (c.x >> 17) & 1023;
        int pos = atomicAdd(&lfill[dlow], 1);
        csr[pos] = make_int2(c.x & 0x1FFFF, c.y);
    }
}

// ------- GEMM2: relu(h1)[N,64] @ W2[64,32] -> h1w2 (fp16) [N,32] -----------
__global__ __launch_bounds__(256) void gemm_h1w2(
    const float* __restrict__ Hin, const float* __restrict__ W2,
    __half* __restrict__ out)
{
    __shared__ float ws[H1 * H2];                      // 8 KiB
    for (int i = threadIdx.x; i < H1 * H2; i += 256) ws[i] = W2[i];
    __syncthreads();

    int row = blockIdx.x * 256 + threadIdx.x;
    if (row >= N_NODES) return;

    const float4* xr = reinterpret_cast<const float4*>(Hin + (size_t)row * H1);
    float4 acc[H2 / 4];
#pragma unroll
    for (int j = 0; j < H2 / 4; ++j) acc[j] = make_float4(0.f, 0.f, 0.f, 0.f);

    for (int k4 = 0; k4 < H1 / 4; ++k4) {
        float4 xv = xr[k4];
        xv.x = fmaxf(xv.x, 0.f); xv.y = fmaxf(xv.y, 0.f);
        xv.z = fmaxf(xv.z, 0.f); xv.w = fmaxf(xv.w, 0.f);
#pragma unroll
        for (int kk = 0; kk < 4; ++kk) {
            float xk = (kk == 0) ? xv.x : (kk == 1) ? xv.y : (kk == 2) ? xv.z : xv.w;
            const float4* wr = reinterpret_cast<const float4*>(&ws[(k4 * 4 + kk) * H2]);
#pragma unroll
            for (int j = 0; j < H2 / 4; ++j) {
                float4 wv = wr[j];
                acc[j].x += xk * wv.x;
                acc[j].y += xk * wv.y;
                acc[j].z += xk * wv.z;
                acc[j].w += xk * wv.w;
            }
        }
    }
    __half2* oh = reinterpret_cast<__half2*>(out + (size_t)row * H2);
#pragma unroll
    for (int j = 0; j < H2 / 4; ++j) {
        oh[j * 2 + 0] = __floats2half2_rn(acc[j].x, acc[j].y);
        oh[j * 2 + 1] = __floats2half2_rn(acc[j].z, acc[j].w);
    }
}

// ---------------- CSR SpMM (gather fp16, accumulate f32) -------------------
__global__ __launch_bounds__(256) void spmm_csr64(
    const int* __restrict__ row_ptr, const int2* __restrict__ csr,
    const __half* __restrict__ xin, float* __restrict__ out)
{
    int gid = blockIdx.x * 256 + threadIdx.x;   // grid covers N*64 exactly
    int node = gid >> 6;
    int f = gid & 63;
    int start = row_ptr[node], end = row_ptr[node + 1];
    float a0 = 0.f, a1 = 0.f, a2 = 0.f, a3 = 0.f;
    int e = start;
    for (; e + 4 <= end; e += 4) {
        int2 c0 = csr[e], c1 = csr[e + 1], c2 = csr[e + 2], c3 = csr[e + 3];
        a0 += __int_as_float(c0.y) * __half2float(xin[(size_t)c0.x * 64 + f]);
        a1 += __int_as_float(c1.y) * __half2float(xin[(size_t)c1.x * 64 + f]);
        a2 += __int_as_float(c2.y) * __half2float(xin[(size_t)c2.x * 64 + f]);
        a3 += __int_as_float(c3.y) * __half2float(xin[(size_t)c3.x * 64 + f]);
    }
    for (; e < end; ++e) {
        int2 c = csr[e];
        a0 += __int_as_float(c.y) * __half2float(xin[(size_t)c.x * 64 + f]);
    }
    out[(size_t)node * 64 + f] = (a0 + a1) + (a2 + a3);
}

__global__ __launch_bounds__(256) void spmm_csr32(
    const int* __restrict__ row_ptr, const int2* __restrict__ csr,
    const __half* __restrict__ xin, float* __restrict__ out)
{
    int gid = blockIdx.x * 256 + threadIdx.x;   // grid covers N*64 exactly
    int node = gid >> 6;
    int f = gid & 31;
    int par = (gid >> 5) & 1;
    int start = row_ptr[node], end = row_ptr[node + 1];
    float a0 = 0.f, a1 = 0.f;
    int e = start + par;
    for (; e + 3 < end; e += 4) {               // this parity: e and e+2
        int2 c0 = csr[e], c1 = csr[e + 2];
        a0 += __int_as_float(c0.y) * __half2float(xin[(size_t)c0.x * 32 + f]);
        a1 += __int_as_float(c1.y) * __half2float(xin[(size_t)c1.x * 32 + f]);
    }
    for (; e < end; e += 2) {
        int2 c = csr[e];
        a0 += __int_as_float(c.y) * __half2float(xin[(size_t)c.x * 32 + f]);
    }
    float acc = a0 + a1;
    acc += __shfl_xor(acc, 32);
    if (par == 0) out[(size_t)node * 32 + f] = acc;
}

extern "C" void kernel_launch(void* const* d_in, const int* in_sizes, int n_in,
                              void* d_out, int out_size, void* d_ws, size_t ws_size,
                              hipStream_t stream)
{
    const float* features    = (const float*)d_in[0];   // [N, 128]
    const float* edge_weight = (const float*)d_in[1];   // [E]
    const float* W1          = (const float*)d_in[2];   // [128, 64]
    const float* W2          = (const float*)d_in[3];   // [64, 32]
    const int*   src         = (const int*)d_in[4];     // [E]
    const int*   dst         = (const int*)d_in[5];     // [E]
    float* out = (float*)d_out;                          // [N, 32]

    // workspace layout; staging aliases h1 (disjoint lifetimes),
    // h1w2h aliases xw1h (xw1h dead after spmm64)
    char* p = (char*)d_ws;
    __half* xw1h    = (__half*)p;               p += (size_t)N_NODES * H1 * 2;  // 12.8MB
    float* h1       = (float*)p;                p += (size_t)N_NODES * H1 * 4;  // 25.6MB
    int2*  csr      = (int2*)p;                 p += (size_t)N_EDGES * 8;       // 12.8MB
    int*   cnt      = (int*)p;                  p += (size_t)N_NODES * 4;
    int*   row_ptr  = (int*)p;                  p += (size_t)(N_NODES + 1) * 4;
    int*   bsum     = (int*)p;                  p += 512 * 4;
    int*   bucket_fill = (int*)p;               p += 128 * 4;
    int2*  staging  = (int2*)h1;
    __half* h1w2h   = xw1h;

    dim3 blk(256);
    int edge_grid = (N_EDGES + 255) / 256;      // 6250

    // --- CSR build (used by both layers); gemm1 fused into pass1 grid ---
    hipMemsetAsync(cnt, 0, (size_t)N_NODES * 4, stream);
    hist_dst<<<edge_grid, blk, 0, stream>>>(dst, cnt);
    scan_block<<<NB1, blk, 0, stream>>>(cnt, bsum);
    scan_top<<<1, 512, 0, stream>>>(bsum);
    scan_add<<<NB1, blk, 0, stream>>>(cnt, bsum, row_ptr, bucket_fill);
    pass1_bin_gemm1<<<P1_WGS + GEMM_WGS, blk, 0, stream>>>(
        src, dst, edge_weight, bucket_fill, staging, features, W1, xw1h);
    pass2_scatter<<<NBUCK, 1024, 0, stream>>>(row_ptr, staging, csr);

    // --- layer 1 aggregate ---
    spmm_csr64<<<(N_NODES * 64) / 256, blk, 0, stream>>>(row_ptr, csr, xw1h, h1);
    // --- layer 2 ---
    gemm_h1w2<<<GEMM_WGS, blk, 0, stream>>>(h1, W2, h1w2h);
    spmm_csr32<<<(N_NODES * 64) / 256, blk, 0, stream>>>(row_ptr, csr, h1w2h, out);
}